// Round 17
// baseline (111.829 us; speedup 1.0000x reference)
//
#include <hip/hip_runtime.h>
#include <hip/hip_bf16.h>
#include <math.h>

#define BATCH 16
#define CH    256
#define HW    1024
#define NS    256
#define NH    16
#define DH    16

typedef __attribute__((ext_vector_type(8))) short short8v;
typedef __attribute__((ext_vector_type(4))) float float4v;

__device__ __forceinline__ unsigned short f2bf(float f) {
    return __builtin_bit_cast(unsigned short, __float2bfloat16(f));
}
__device__ __forceinline__ unsigned pack2(float lo, float hi) {
    return (unsigned)f2bf(lo) | ((unsigned)f2bf(hi) << 16);
}

// ---------------------------------------------------------------------------
// prep: blocks 0..1023   -> weight repack (4 matrices, A-frag order)
//       blocks 1024..1279 -> x[b][c][p] fp32 -> xT[b][p][c] bf16
// Wf[mat][((ot*8+kt)*64+l)*8+i] = W[ot*16+(l&15)][kt*32+8*(l>>4)+i]
// ---------------------------------------------------------------------------
__global__ __launch_bounds__(256) void prep_k(
    const float* __restrict__ wq, const float* __restrict__ wk,
    const float* __restrict__ wv, const float* __restrict__ wo,
    unsigned short* __restrict__ Wf,
    const float* __restrict__ x, unsigned short* __restrict__ xT)
{
    int blk = blockIdx.x;
    if (blk < 1024) {
        const float* W;
        switch (blk >> 8) {
            case 0: W = wq; break;
            case 1: W = wk; break;
            case 2: W = wv; break;
            default: W = wo; break;
        }
        int e = (blk & 255) * 256 + threadIdx.x;     // 0..65535
        int i = e & 7, l = (e >> 3) & 63, kt = (e >> 9) & 7, ot = e >> 12;
        float v = W[(ot * 16 + (l & 15)) * 256 + kt * 32 + 8 * (l >> 4) + i];
        Wf[(blk >> 8) * 65536 + e] = f2bf(v);
    } else {
        int xb = blk - 1024;                          // 0..255
        int b = xb >> 4, pblk = (xb >> 2) & 3, cblk = xb & 3;
        int p = pblk * 256 + threadIdx.x;
        const float* xp = x + (size_t)b * CH * HW + p;
        unsigned short* o = xT + ((size_t)b * HW + p) * CH;
        #pragma unroll
        for (int cc = 0; cc < 64; cc += 8) {
            int c0 = cblk * 64 + cc;
            short8v t;
            #pragma unroll
            for (int i = 0; i < 8; ++i) t[i] = (short)f2bf(xp[(size_t)(c0 + i) * HW]);
            *(short8v*)&o[c0] = t;
        }
    }
}

// ---------------------------------------------------------------------------
// bf16 MFMA GEMM conv1x1 (packed Wf): C[o][p] = W[o][:] . X[:][p]  (K=256)
// 64x64 tile (wave = 64o x 16p strip, 32 MFMA); grid (4, P/64, B) = 4 blk/CU.
// MODE 0: Q  -> outF fp32 [b][o][p] + outB bf16 qH [b][h][p][16] (pre-scaled 0.25)
// MODE 2: O  -> outF fp32 d_out with BN epilogue; XT is aoH [b][h][m][16]
// ---------------------------------------------------------------------------
template<int P, int MODE>
__global__ __launch_bounds__(256) void gemm_k(
    const unsigned short* __restrict__ Wf, const unsigned short* __restrict__ XT,
    const float* __restrict__ bias,
    float* __restrict__ outF, unsigned short* __restrict__ outB,
    const float* __restrict__ bn_g, const float* __restrict__ bn_b,
    const float* __restrict__ bn_m, const float* __restrict__ bn_v)
{
    const int b = blockIdx.z;

    const int t = threadIdx.x, lane = t & 63, wvi = t >> 6;
    const int g = lane >> 4, col = lane & 15;
    const int o0 = blockIdx.x * 64;
    const int p0 = blockIdx.y * 64 + wvi * 16;
    const unsigned short* xb = XT + ((size_t)b * P + p0) * CH;   // MODE 0

    float4v acc[4];
    #pragma unroll
    for (int mi = 0; mi < 4; ++mi) {
        float4v z = {0.f, 0.f, 0.f, 0.f};
        acc[mi] = z;
    }

    #pragma unroll
    for (int kt = 0; kt < 8; ++kt) {
        short8v af[4], bf;
        #pragma unroll
        for (int mi = 0; mi < 4; ++mi)
            af[mi] = *(const short8v*)&Wf[(((((o0 >> 4) + mi) * 8) + kt) * 64 + lane) * 8];
        if (MODE == 2) {
            // aoH head-major: channels kt*32+8g..+7 lie inside head hh
            const int hh = kt * 2 + (g >> 1);
            const int p  = p0 + col;
            bf = *(const short8v*)&XT[(((size_t)(b * 16 + hh) * P + p) << 4) + 8 * (g & 1)];
        } else {
            bf = *(const short8v*)&xb[(size_t)col * CH + kt * 32 + 8 * g];
        }
        #pragma unroll
        for (int mi = 0; mi < 4; ++mi)
            acc[mi] = __builtin_amdgcn_mfma_f32_16x16x32_bf16(af[mi], bf, acc[mi], 0, 0, 0);
    }

    #pragma unroll
    for (int mi = 0; mi < 4; ++mi) {
        const int ob = o0 + mi * 16 + 4 * g;
        float bs[4];
        #pragma unroll
        for (int ii = 0; ii < 4; ++ii) bs[ii] = bias[ob + ii];

        if (MODE == 2) {
            float sc[4], sh[4];
            #pragma unroll
            for (int ii = 0; ii < 4; ++ii) {
                int o = ob + ii;
                float s = bn_g[o] * rsqrtf(bn_v[o] + 1e-5f);
                sc[ii] = s;
                sh[ii] = bn_b[o] - bn_m[o] * s + bs[ii] * s;
            }
            int p = p0 + col;
            #pragma unroll
            for (int ii = 0; ii < 4; ++ii)
                outF[((size_t)(b * CH + ob + ii)) * P + p] =
                    acc[mi][ii] * sc[ii] + sh[ii];
        } else {
            const int hh = (o0 >> 4) + mi;     // head index (4g < 16)
            int p = p0 + col;
            float v0 = acc[mi][0] + bs[0];
            float v1 = acc[mi][1] + bs[1];
            float v2 = acc[mi][2] + bs[2];
            float v3 = acc[mi][3] + bs[3];
            outF[((size_t)(b * CH + ob + 0)) * P + p] = v0;
            outF[((size_t)(b * CH + ob + 1)) * P + p] = v1;
            outF[((size_t)(b * CH + ob + 2)) * P + p] = v2;
            outF[((size_t)(b * CH + ob + 3)) * P + p] = v3;
            uint2 w;   // qH pre-scaled by 0.25 (exact pow2)
            w.x = pack2(v0 * 0.25f, v1 * 0.25f);
            w.y = pack2(v2 * 0.25f, v3 * 0.25f);
            *(uint2*)&outB[(((size_t)(b * 16 + hh) * P + p) << 4) + 4 * g] = w;
        }
    }
}

// ---------------------------------------------------------------------------
// depthwise 9x9 conv, stride 2, pad 4:
// q fp32 [b][c][32][32] -> offT fp32 [b][s][c]  (transposed write)
// ---------------------------------------------------------------------------
__global__ __launch_bounds__(256) void dwconv_k(
    const float* __restrict__ q, const float* __restrict__ w,
    const float* __restrict__ bias, float* __restrict__ offT)
{
    int bc = blockIdx.x;
    int b  = bc >> 8;
    int c  = bc & (CH - 1);
    __shared__ float plane[HW];
    __shared__ float kw[81];
    int t = threadIdx.x;
    const float* qp = q + (size_t)bc * HW;
    #pragma unroll
    for (int j = t; j < HW; j += 256) plane[j] = qp[j];
    if (t < 81) kw[t] = w[c * 81 + t];
    __syncthreads();
    int hk = t >> 4, wk = t & 15;
    float s = bias[c];
    int yb = hk * 2 - 4, xb = wk * 2 - 4;
    #pragma unroll
    for (int dy = 0; dy < 9; ++dy) {
        int yy = yb + dy;
        if ((unsigned)yy < 32u) {
            #pragma unroll
            for (int dx = 0; dx < 9; ++dx) {
                int xx = xb + dx;
                if ((unsigned)xx < 32u) s += kw[dy * 9 + dx] * plane[yy * 32 + xx];
            }
        }
    }
    offT[((size_t)(b * NS + t)) * CH + c] = s;
}

// ---------------------------------------------------------------------------
// fused: LN(channel) + GELU + projection + ref + tanh + bilinear grid sample
// offT read coalesced; tanh => all 4 taps statically in-bounds.
// -> xsT bf16 [b][s][c]
// ---------------------------------------------------------------------------
__device__ inline void block_reduce2(float& a, float& b, int t, float* sbuf)
{
    #pragma unroll
    for (int o = 32; o > 0; o >>= 1) {
        a += __shfl_down(a, o);
        b += __shfl_down(b, o);
    }
    int w = t >> 6;
    if ((t & 63) == 0) { sbuf[w * 2] = a; sbuf[w * 2 + 1] = b; }
    __syncthreads();
    a = sbuf[0] + sbuf[2] + sbuf[4] + sbuf[6];
    b = sbuf[1] + sbuf[3] + sbuf[5] + sbuf[7];
    __syncthreads();
}

__global__ __launch_bounds__(256) void lngs_k(
    const float* __restrict__ offT, const float* __restrict__ ln_g,
    const float* __restrict__ ln_b, const float* __restrict__ pw,
    const float* __restrict__ x, unsigned short* __restrict__ xsT)
{
    __shared__ float sbuf[8];
    int bs = blockIdx.x;
    int b = bs >> 8, s = bs & 255;
    int c = threadIdx.x;
    float v = offT[(size_t)bs * CH + c];
    float a = v, q2 = v * v;
    block_reduce2(a, q2, c, sbuf);
    float mean = a * (1.0f / 256.0f);
    float var  = q2 * (1.0f / 256.0f) - mean * mean;
    float xn = (v - mean) * rsqrtf(var + 1e-5f) * ln_g[c] + ln_b[c];
    float g = 0.5f * xn * (1.0f + erff(xn * 0.70710678118654752f));
    float d0 = g * pw[c];
    float d1 = g * pw[CH + c];
    block_reduce2(d0, d1, c, sbuf);   // broadcasts sums to all threads

    int hk = s >> 4, wk = s & 15;
    float ry = ((hk + 0.5f) / 16.0f) * 2.0f - 1.0f;
    float rx = ((wk + 0.5f) / 16.0f) * 2.0f - 1.0f;
    float py = tanhf(d0 + ry);
    float px = tanhf(d1 + rx);

    float gx = (px + 1.0f) * 0.5f * 31.0f;
    float gy = (py + 1.0f) * 0.5f * 31.0f;
    float x0f = floorf(gx), y0f = floorf(gy);
    int ix = (int)x0f, iy = (int)y0f;
    float wx1 = gx - x0f, wx0 = 1.0f - wx1;
    float wy1 = gy - y0f, wy0 = 1.0f - wy1;
    const float* img = x + ((size_t)b * CH + c) * HW;
    float v00 = img[iy * 32 + ix];
    float v01 = img[iy * 32 + ix + 1];
    float v10 = img[(iy + 1) * 32 + ix];
    float v11 = img[(iy + 1) * 32 + ix + 1];
    float vv = wy0 * wx0 * v00 + wy0 * wx1 * v01 + wy1 * wx0 * v10 + wy1 * wx1 * v11;
    xsT[(size_t)bs * CH + c] = f2bf(vv);
}

// ---------------------------------------------------------------------------
// fused KV-build + MFMA attention. Grid = (b,h,mhalf): 512 blocks x 1024 thr.
// Wave wvi builds K/V n-tile wvi, then attn over its 32 query rows.
// Softmax without max-subtraction: |s| <= ~4 by construction (fp32 exp safe);
// the common factor cancels exactly in <p,v>/sum(p).
// ---------------------------------------------------------------------------
__global__ __launch_bounds__(1024) void attn_fused_k(
    const unsigned short* __restrict__ qH, const unsigned short* __restrict__ xsT,
    const unsigned short* __restrict__ Wf,
    const float* __restrict__ bk, const float* __restrict__ bv,
    unsigned short* __restrict__ aoH)
{
    const int bh    = blockIdx.x >> 1;
    const int mhalf = blockIdx.x & 1;
    const int b = bh >> 4, h = bh & 15;

    __shared__ short Kp[16 * 32 * 8 + 8];   // 8KB + 16B zero slot (QK A-frag)
    __shared__ short Vp[8 * 64 * 8];        // 8KB PV A-frag (8 chunks of n=32)
    __shared__ short Ps[16][16 * 32];       // 16KB per-wave P scratch

    const int tid  = threadIdx.x;
    const int lane = tid & 63;
    const int wvi  = tid >> 6;      // 0..15
    const int col  = lane & 15;
    const int g    = lane >> 4;

    {
        const unsigned short* WfK = Wf + 1 * 65536 + h * 4096;
        const unsigned short* WfV = Wf + 2 * 65536 + h * 4096;
        float bk4[4];
        #pragma unroll
        for (int j = 0; j < 4; ++j) bk4[j] = bk[h * 16 + 4 * g + j];
        const float bvv = bv[h * 16 + col];

        const int t  = wvi;
        const int n0 = t * 16;
        float4v accK = {0.f, 0.f, 0.f, 0.f};
        float4v accV = {0.f, 0.f, 0.f, 0.f};
        #pragma unroll
        for (int kt = 0; kt < 8; ++kt) {
            short8v xsf = *(const short8v*)&xsT[((size_t)(b * NS + n0 + col)) * CH + kt * 32 + 8 * g];
            short8v wkf = *(const short8v*)&WfK[(kt * 64 + lane) * 8];
            short8v wvf = *(const short8v*)&WfV[(kt * 64 + lane) * 8];
            accK = __builtin_amdgcn_mfma_f32_16x16x32_bf16(wkf, xsf, accK, 0, 0, 0);
            accV = __builtin_amdgcn_mfma_f32_16x16x32_bf16(xsf, wvf, accV, 0, 0, 0);
        }
        uint2 wrk;
        wrk.x = pack2(accK[0] + bk4[0], accK[1] + bk4[1]);
        wrk.y = pack2(accK[2] + bk4[2], accK[3] + bk4[3]);
        *(uint2*)&Kp[(t * 32 + (g >> 1) * 16 + col) * 8 + 4 * (g & 1)] = wrk;
        uint2 wrv;
        wrv.x = pack2(accV[0] + bvv, accV[1] + bvv);
        wrv.y = pack2(accV[2] + bvv, accV[3] + bvv);
        *(uint2*)&Vp[((t >> 1) * 64 + col + 16 * ((2 * t + (g >> 1)) & 3)) * 8 + 4 * (g & 1)] = wrv;
    }
    if (tid == 0) {
        short8v z = {0, 0, 0, 0, 0, 0, 0, 0};
        *(short8v*)&Kp[16 * 32 * 8] = z;
    }
    __syncthreads();

    const unsigned short* Qb = qH + ((size_t)(b * 16 + h) * HW << 4);
    unsigned short*       Ob = aoH + ((size_t)(b * 16 + h) * HW << 4);
    char* pbase = (char*)Ps[wvi];
    const char* kbase = (const char*)Kp + ((lane < 32) ? lane * 16 : 16 * 32 * 16);
    const int   kstep = (lane < 32) ? 512 : 0;

    #pragma unroll
    for (int mt = 0; mt < 2; ++mt) {
        const int m0 = mhalf * 512 + wvi * 32 + mt * 16;

        short8v qf = {0, 0, 0, 0, 0, 0, 0, 0};
        if (g < 2)
            qf = *(const short8v*)&Qb[((m0 + col) << 4) + 8 * g];

        float4v p[16];
        #pragma unroll
        for (int t = 0; t < 16; ++t) {
            short8v kf = *(const short8v*)(kbase + t * kstep);
            float4v z = {0.f, 0.f, 0.f, 0.f};
            p[t] = __builtin_amdgcn_mfma_f32_16x16x32_bf16(kf, qf, z, 0, 0, 0);
        }

        float s4[4] = {0.f, 0.f, 0.f, 0.f};
        #pragma unroll
        for (int t = 0; t < 16; ++t) {
            #pragma unroll
            for (int i = 0; i < 4; ++i) {
                float e = __expf(p[t][i]);   // 0.25 pre-folded into qH; no max needed
                p[t][i] = e;
                s4[i] += e;
            }
        }
        float sum = (s4[0] + s4[1]) + (s4[2] + s4[3]);
        sum += __shfl_xor(sum, 16);
        sum += __shfl_xor(sum, 32);
        const float inv = 1.0f / sum;

        float4v acc = {0.f, 0.f, 0.f, 0.f};
        #pragma unroll
        for (int c = 0; c < 8; ++c) {
            #pragma unroll
            for (int pp = 0; pp < 2; ++pp) {
                float4v pv = p[2 * c + pp];
                uint2 wr;
                wr.x = pack2(pv[0], pv[1]);
                wr.y = pack2(pv[2], pv[3]);
                *(uint2*)(pbase + ((col * 64 + (16 * pp + 4 * g) * 2) ^ ((col & 7) << 4))) = wr;
            }
            short8v pf = *(const short8v*)(pbase + ((col * 64 + 16 * g) ^ ((col & 7) << 4)));
            short8v vf = *(const short8v*)&Vp[(c * 64 + lane) * 8];
            acc = __builtin_amdgcn_mfma_f32_16x16x32_bf16(vf, pf, acc, 0, 0, 0);
        }

        uint2 w;
        w.x = pack2(acc[0] * inv, acc[1] * inv);
        w.y = pack2(acc[2] * inv, acc[3] * inv);
        *(uint2*)&Ob[((m0 + col) << 4) + 4 * g] = w;
    }
}

// ---------------------------------------------------------------------------
extern "C" void kernel_launch(void* const* d_in, const int* in_sizes, int n_in,
                              void* d_out, int out_size, void* d_ws, size_t ws_size,
                              hipStream_t stream)
{
    const float* x        = (const float*)d_in[0];
    const float* wq       = (const float*)d_in[1];
    const float* bq       = (const float*)d_in[2];
    const float* off_dw_w = (const float*)d_in[3];
    const float* off_dw_b = (const float*)d_in[4];
    const float* ln_g     = (const float*)d_in[5];
    const float* ln_b     = (const float*)d_in[6];
    const float* off_pw_w = (const float*)d_in[7];
    const float* wk       = (const float*)d_in[8];
    const float* bk       = (const float*)d_in[9];
    const float* wv       = (const float*)d_in[10];
    const float* bv       = (const float*)d_in[11];
    const float* wo       = (const float*)d_in[12];
    const float* bo       = (const float*)d_in[13];
    const float* bn_g     = (const float*)d_in[14];
    const float* bn_b     = (const float*)d_in[15];
    const float* bn_m     = (const float*)d_in[16];
    const float* bn_v     = (const float*)d_in[17];

    float* ws   = (float*)d_ws;
    float* q    = ws;                       // 4194304 f (fp32 for dwconv)
    float* offT = q + 4194304;              // 1048576 f [b][s][c]
    unsigned short* us  = (unsigned short*)(offT + 1048576);
    unsigned short* Wf  = us;               //  262144 us (4 frag-packed weights)
    unsigned short* xT  = Wf  + 262144;     // 4194304 us
    unsigned short* qH  = xT  + 4194304;    // 4194304 us  [b][h][m][16]
    unsigned short* xsT = qH  + 4194304;    // 1048576 us
    unsigned short* aoH = xsT + 1048576;    // 4194304 us  [b][h][m][16]

    prep_k<<<1280, 256, 0, stream>>>(wq, wk, wv, wo, Wf, x, xT);
    gemm_k<HW, 0><<<dim3(4, 16, BATCH), 256, 0, stream>>>(
        Wf, xT, bq, q, qH, nullptr, nullptr, nullptr, nullptr);
    dwconv_k<<<BATCH * CH, 256, 0, stream>>>(q, off_dw_w, off_dw_b, offT);
    lngs_k<<<BATCH * NS, 256, 0, stream>>>(offT, ln_g, ln_b, off_pw_w, x, xsT);
    attn_fused_k<<<BATCH * NH * 2, 1024, 0, stream>>>(qH, xsT, Wf, bk, bv, aoH);
    gemm_k<HW, 2><<<dim3(4, 16, BATCH), 256, 0, stream>>>(
        Wf + 3 * 65536, aoH, bo, (float*)d_out, nullptr,
        bn_g, bn_b, bn_m, bn_v);
}

// Round 18
// 107.837 us; speedup vs baseline: 1.0370x; 1.0370x over previous
//
#include <hip/hip_runtime.h>
#include <hip/hip_bf16.h>
#include <math.h>

#define BATCH 16
#define CH    256
#define HW    1024
#define NS    256
#define NH    16
#define DH    16

typedef __attribute__((ext_vector_type(8))) short short8v;
typedef __attribute__((ext_vector_type(4))) float float4v;

__device__ __forceinline__ unsigned short f2bf(float f) {
    return __builtin_bit_cast(unsigned short, __float2bfloat16(f));
}
__device__ __forceinline__ unsigned pack2(float lo, float hi) {
    return (unsigned)f2bf(lo) | ((unsigned)f2bf(hi) << 16);
}

// ---------------------------------------------------------------------------
// prep: blocks 0..1023   -> weight repack (4 matrices, A-frag order)
//       blocks 1024..1279 -> x[b][c][p] fp32 -> xT[b][p][c] bf16
//                            AND xPf[b][p][c] fp32 (for lngs's coalesced taps)
// Wf[mat][((ot*8+kt)*64+l)*8+i] = W[ot*16+(l&15)][kt*32+8*(l>>4)+i]
// ---------------------------------------------------------------------------
__global__ __launch_bounds__(256) void prep_k(
    const float* __restrict__ wq, const float* __restrict__ wk,
    const float* __restrict__ wv, const float* __restrict__ wo,
    unsigned short* __restrict__ Wf,
    const float* __restrict__ x, unsigned short* __restrict__ xT,
    float* __restrict__ xPf)
{
    int blk = blockIdx.x;
    if (blk < 1024) {
        const float* W;
        switch (blk >> 8) {
            case 0: W = wq; break;
            case 1: W = wk; break;
            case 2: W = wv; break;
            default: W = wo; break;
        }
        int e = (blk & 255) * 256 + threadIdx.x;     // 0..65535
        int i = e & 7, l = (e >> 3) & 63, kt = (e >> 9) & 7, ot = e >> 12;
        float v = W[(ot * 16 + (l & 15)) * 256 + kt * 32 + 8 * (l >> 4) + i];
        Wf[(blk >> 8) * 65536 + e] = f2bf(v);
    } else {
        int xb = blk - 1024;                          // 0..255
        int b = xb >> 4, pblk = (xb >> 2) & 3, cblk = xb & 3;
        int p = pblk * 256 + threadIdx.x;
        const float* xp = x + (size_t)b * CH * HW + p;
        unsigned short* o = xT + ((size_t)b * HW + p) * CH;
        float* o2 = xPf + ((size_t)b * HW + p) * CH;
        #pragma unroll
        for (int cc = 0; cc < 64; cc += 8) {
            int c0 = cblk * 64 + cc;
            float4 lo, hi;
            lo.x = xp[(size_t)(c0 + 0) * HW];
            lo.y = xp[(size_t)(c0 + 1) * HW];
            lo.z = xp[(size_t)(c0 + 2) * HW];
            lo.w = xp[(size_t)(c0 + 3) * HW];
            hi.x = xp[(size_t)(c0 + 4) * HW];
            hi.y = xp[(size_t)(c0 + 5) * HW];
            hi.z = xp[(size_t)(c0 + 6) * HW];
            hi.w = xp[(size_t)(c0 + 7) * HW];
            short8v t;
            t[0] = (short)f2bf(lo.x); t[1] = (short)f2bf(lo.y);
            t[2] = (short)f2bf(lo.z); t[3] = (short)f2bf(lo.w);
            t[4] = (short)f2bf(hi.x); t[5] = (short)f2bf(hi.y);
            t[6] = (short)f2bf(hi.z); t[7] = (short)f2bf(hi.w);
            *(short8v*)&o[c0] = t;
            *(float4*)&o2[c0]     = lo;
            *(float4*)&o2[c0 + 4] = hi;
        }
    }
}

// ---------------------------------------------------------------------------
// bf16 MFMA GEMM conv1x1 (packed Wf): C[o][p] = W[o][:] . X[:][p]  (K=256)
// 64x128 tile, 4 waves, no LDS (R16 config).
// MODE 0: Q  -> outF fp32 [b][o][p] + outB bf16 qH [b][h][p][16] (pre-scaled 0.25)
// MODE 2: O  -> outF fp32 d_out with BN epilogue; XT is aoH [b][h][m][16]
// ---------------------------------------------------------------------------
template<int P, int MODE>
__global__ __launch_bounds__(256) void gemm_k(
    const unsigned short* __restrict__ Wf, const unsigned short* __restrict__ XT,
    const float* __restrict__ bias,
    float* __restrict__ outF, unsigned short* __restrict__ outB,
    const float* __restrict__ bn_g, const float* __restrict__ bn_b,
    const float* __restrict__ bn_m, const float* __restrict__ bn_v)
{
    const int b = blockIdx.z;

    const int t = threadIdx.x, lane = t & 63, wvi = t >> 6;
    const int g = lane >> 4, col = lane & 15;
    const int o0 = blockIdx.x * 64;
    const int p0 = blockIdx.y * 128 + wvi * 32;
    const unsigned short* xb = XT + ((size_t)b * P + p0) * CH;   // MODE 0

    float4v acc[4][2];
    #pragma unroll
    for (int mi = 0; mi < 4; ++mi)
        #pragma unroll
        for (int ni = 0; ni < 2; ++ni) {
            float4v z = {0.f, 0.f, 0.f, 0.f};
            acc[mi][ni] = z;
        }

    #pragma unroll
    for (int kt = 0; kt < 8; ++kt) {
        short8v af[4], bf[2];
        #pragma unroll
        for (int mi = 0; mi < 4; ++mi)
            af[mi] = *(const short8v*)&Wf[(((((o0 >> 4) + mi) * 8) + kt) * 64 + lane) * 8];
        #pragma unroll
        for (int ni = 0; ni < 2; ++ni) {
            if (MODE == 2) {
                // aoH head-major: channels kt*32+8g..+7 lie inside head hh
                const int hh = kt * 2 + (g >> 1);
                const int p  = p0 + ni * 16 + col;
                bf[ni] = *(const short8v*)&XT[(((size_t)(b * 16 + hh) * P + p) << 4) + 8 * (g & 1)];
            } else {
                bf[ni] = *(const short8v*)&xb[(size_t)(ni * 16 + col) * CH + kt * 32 + 8 * g];
            }
        }
        #pragma unroll
        for (int mi = 0; mi < 4; ++mi)
            #pragma unroll
            for (int ni = 0; ni < 2; ++ni)
                acc[mi][ni] = __builtin_amdgcn_mfma_f32_16x16x32_bf16(
                    af[mi], bf[ni], acc[mi][ni], 0, 0, 0);
    }

    #pragma unroll
    for (int mi = 0; mi < 4; ++mi) {
        const int ob = o0 + mi * 16 + 4 * g;
        float bs[4];
        #pragma unroll
        for (int ii = 0; ii < 4; ++ii) bs[ii] = bias[ob + ii];

        if (MODE == 2) {
            float sc[4], sh[4];
            #pragma unroll
            for (int ii = 0; ii < 4; ++ii) {
                int o = ob + ii;
                float s = bn_g[o] * rsqrtf(bn_v[o] + 1e-5f);
                sc[ii] = s;
                sh[ii] = bn_b[o] - bn_m[o] * s + bs[ii] * s;
            }
            #pragma unroll
            for (int ni = 0; ni < 2; ++ni) {
                int p = p0 + ni * 16 + col;
                #pragma unroll
                for (int ii = 0; ii < 4; ++ii)
                    outF[((size_t)(b * CH + ob + ii)) * P + p] =
                        acc[mi][ni][ii] * sc[ii] + sh[ii];
            }
        } else {
            const int hh = (o0 >> 4) + mi;     // head index (4g < 16)
            #pragma unroll
            for (int ni = 0; ni < 2; ++ni) {
                int p = p0 + ni * 16 + col;
                float v0 = acc[mi][ni][0] + bs[0];
                float v1 = acc[mi][ni][1] + bs[1];
                float v2 = acc[mi][ni][2] + bs[2];
                float v3 = acc[mi][ni][3] + bs[3];
                outF[((size_t)(b * CH + ob + 0)) * P + p] = v0;
                outF[((size_t)(b * CH + ob + 1)) * P + p] = v1;
                outF[((size_t)(b * CH + ob + 2)) * P + p] = v2;
                outF[((size_t)(b * CH + ob + 3)) * P + p] = v3;
                uint2 w;   // qH pre-scaled by 0.25 (exact pow2)
                w.x = pack2(v0 * 0.25f, v1 * 0.25f);
                w.y = pack2(v2 * 0.25f, v3 * 0.25f);
                *(uint2*)&outB[(((size_t)(b * 16 + hh) * P + p) << 4) + 4 * g] = w;
            }
        }
    }
}

// ---------------------------------------------------------------------------
// depthwise 9x9 conv, stride 2, pad 4:
// q fp32 [b][c][32][32] -> offT fp32 [b][s][c]  (transposed write)
// ---------------------------------------------------------------------------
__global__ __launch_bounds__(256) void dwconv_k(
    const float* __restrict__ q, const float* __restrict__ w,
    const float* __restrict__ bias, float* __restrict__ offT)
{
    int bc = blockIdx.x;
    int b  = bc >> 8;
    int c  = bc & (CH - 1);
    __shared__ float plane[HW];
    __shared__ float kw[81];
    int t = threadIdx.x;
    const float* qp = q + (size_t)bc * HW;
    #pragma unroll
    for (int j = t; j < HW; j += 256) plane[j] = qp[j];
    if (t < 81) kw[t] = w[c * 81 + t];
    __syncthreads();
    int hk = t >> 4, wk = t & 15;
    float s = bias[c];
    int yb = hk * 2 - 4, xb = wk * 2 - 4;
    #pragma unroll
    for (int dy = 0; dy < 9; ++dy) {
        int yy = yb + dy;
        if ((unsigned)yy < 32u) {
            #pragma unroll
            for (int dx = 0; dx < 9; ++dx) {
                int xx = xb + dx;
                if ((unsigned)xx < 32u) s += kw[dy * 9 + dx] * plane[yy * 32 + xx];
            }
        }
    }
    offT[((size_t)(b * NS + t)) * CH + c] = s;
}

// ---------------------------------------------------------------------------
// fused: LN(channel) + GELU + projection + ref + tanh + bilinear grid sample
// offT read coalesced; taps read from xPf[b][p][c] fp32 (dense 1KB runs).
// tanh => all 4 taps statically in-bounds. -> xsT bf16 [b][s][c]
// ---------------------------------------------------------------------------
__device__ inline void block_reduce2(float& a, float& b, int t, float* sbuf)
{
    #pragma unroll
    for (int o = 32; o > 0; o >>= 1) {
        a += __shfl_down(a, o);
        b += __shfl_down(b, o);
    }
    int w = t >> 6;
    if ((t & 63) == 0) { sbuf[w * 2] = a; sbuf[w * 2 + 1] = b; }
    __syncthreads();
    a = sbuf[0] + sbuf[2] + sbuf[4] + sbuf[6];
    b = sbuf[1] + sbuf[3] + sbuf[5] + sbuf[7];
    __syncthreads();
}

__global__ __launch_bounds__(256) void lngs_k(
    const float* __restrict__ offT, const float* __restrict__ ln_g,
    const float* __restrict__ ln_b, const float* __restrict__ pw,
    const float* __restrict__ xPf, unsigned short* __restrict__ xsT)
{
    __shared__ float sbuf[8];
    int bs = blockIdx.x;
    int b = bs >> 8, s = bs & 255;
    int c = threadIdx.x;
    float v = offT[(size_t)bs * CH + c];
    float a = v, q2 = v * v;
    block_reduce2(a, q2, c, sbuf);
    float mean = a * (1.0f / 256.0f);
    float var  = q2 * (1.0f / 256.0f) - mean * mean;
    float xn = (v - mean) * rsqrtf(var + 1e-5f) * ln_g[c] + ln_b[c];
    float g = 0.5f * xn * (1.0f + erff(xn * 0.70710678118654752f));
    float d0 = g * pw[c];
    float d1 = g * pw[CH + c];
    block_reduce2(d0, d1, c, sbuf);   // broadcasts sums to all threads

    int hk = s >> 4, wk = s & 15;
    float ry = ((hk + 0.5f) / 16.0f) * 2.0f - 1.0f;
    float rx = ((wk + 0.5f) / 16.0f) * 2.0f - 1.0f;
    float py = tanhf(d0 + ry);
    float px = tanhf(d1 + rx);

    float gx = (px + 1.0f) * 0.5f * 31.0f;
    float gy = (py + 1.0f) * 0.5f * 31.0f;
    float x0f = floorf(gx), y0f = floorf(gy);
    int ix = (int)x0f, iy = (int)y0f;
    float wx1 = gx - x0f, wx0 = 1.0f - wx1;
    float wy1 = gy - y0f, wy0 = 1.0f - wy1;
    const float* base = xPf + ((size_t)b * HW + iy * 32 + ix) * CH + c;
    float v00 = base[0];
    float v01 = base[CH];
    float v10 = base[32 * CH];
    float v11 = base[33 * CH];
    float vv = wy0 * wx0 * v00 + wy0 * wx1 * v01 + wy1 * wx0 * v10 + wy1 * wx1 * v11;
    xsT[(size_t)bs * CH + c] = f2bf(vv);
}

// ---------------------------------------------------------------------------
// fused KV-build + MFMA attention (R16 config: tree-max softmax).
// Grid = (b,h,mhalf): 512 blocks x 1024 thr. Wave wvi builds K/V n-tile wvi,
// then attn over its 32 query rows. Head-major I/O.
// ---------------------------------------------------------------------------
__global__ __launch_bounds__(1024) void attn_fused_k(
    const unsigned short* __restrict__ qH, const unsigned short* __restrict__ xsT,
    const unsigned short* __restrict__ Wf,
    const float* __restrict__ bk, const float* __restrict__ bv,
    unsigned short* __restrict__ aoH)
{
    const int bh    = blockIdx.x >> 1;
    const int mhalf = blockIdx.x & 1;
    const int b = bh >> 4, h = bh & 15;

    __shared__ short Kp[16 * 32 * 8 + 8];   // 8KB + 16B zero slot (QK A-frag)
    __shared__ short Vp[8 * 64 * 8];        // 8KB PV A-frag (8 chunks of n=32)
    __shared__ short Ps[16][16 * 32];       // 16KB per-wave P scratch

    const int tid  = threadIdx.x;
    const int lane = tid & 63;
    const int wvi  = tid >> 6;      // 0..15
    const int col  = lane & 15;
    const int g    = lane >> 4;

    {
        const unsigned short* WfK = Wf + 1 * 65536 + h * 4096;
        const unsigned short* WfV = Wf + 2 * 65536 + h * 4096;
        float bk4[4];
        #pragma unroll
        for (int j = 0; j < 4; ++j) bk4[j] = bk[h * 16 + 4 * g + j];
        const float bvv = bv[h * 16 + col];

        const int t  = wvi;
        const int n0 = t * 16;
        float4v accK = {0.f, 0.f, 0.f, 0.f};
        float4v accV = {0.f, 0.f, 0.f, 0.f};
        #pragma unroll
        for (int kt = 0; kt < 8; ++kt) {
            short8v xsf = *(const short8v*)&xsT[((size_t)(b * NS + n0 + col)) * CH + kt * 32 + 8 * g];
            short8v wkf = *(const short8v*)&WfK[(kt * 64 + lane) * 8];
            short8v wvf = *(const short8v*)&WfV[(kt * 64 + lane) * 8];
            accK = __builtin_amdgcn_mfma_f32_16x16x32_bf16(wkf, xsf, accK, 0, 0, 0);
            accV = __builtin_amdgcn_mfma_f32_16x16x32_bf16(xsf, wvf, accV, 0, 0, 0);
        }
        uint2 wrk;
        wrk.x = pack2(accK[0] + bk4[0], accK[1] + bk4[1]);
        wrk.y = pack2(accK[2] + bk4[2], accK[3] + bk4[3]);
        *(uint2*)&Kp[(t * 32 + (g >> 1) * 16 + col) * 8 + 4 * (g & 1)] = wrk;
        uint2 wrv;
        wrv.x = pack2(accV[0] + bvv, accV[1] + bvv);
        wrv.y = pack2(accV[2] + bvv, accV[3] + bvv);
        *(uint2*)&Vp[((t >> 1) * 64 + col + 16 * ((2 * t + (g >> 1)) & 3)) * 8 + 4 * (g & 1)] = wrv;
    }
    if (tid == 0) {
        short8v z = {0, 0, 0, 0, 0, 0, 0, 0};
        *(short8v*)&Kp[16 * 32 * 8] = z;
    }
    __syncthreads();

    const unsigned short* Qb = qH + ((size_t)(b * 16 + h) * HW << 4);
    unsigned short*       Ob = aoH + ((size_t)(b * 16 + h) * HW << 4);
    char* pbase = (char*)Ps[wvi];
    const char* kbase = (const char*)Kp + ((lane < 32) ? lane * 16 : 16 * 32 * 16);
    const int   kstep = (lane < 32) ? 512 : 0;

    #pragma unroll
    for (int mt = 0; mt < 2; ++mt) {
        const int m0 = mhalf * 512 + wvi * 32 + mt * 16;

        short8v qf = {0, 0, 0, 0, 0, 0, 0, 0};
        if (g < 2)
            qf = *(const short8v*)&Qb[((m0 + col) << 4) + 8 * g];

        float4v p[16];
        #pragma unroll
        for (int t = 0; t < 16; ++t) {
            short8v kf = *(const short8v*)(kbase + t * kstep);
            float4v z = {0.f, 0.f, 0.f, 0.f};
            p[t] = __builtin_amdgcn_mfma_f32_16x16x32_bf16(kf, qf, z, 0, 0, 0);
        }

        float mx4[16];
        #pragma unroll
        for (int t = 0; t < 16; ++t)
            mx4[t] = fmaxf(fmaxf(p[t][0], p[t][1]), fmaxf(p[t][2], p[t][3]));
        #pragma unroll
        for (int o = 8; o >= 1; o >>= 1)
            #pragma unroll
            for (int i = 0; i < 8; ++i)
                if (i < o) mx4[i] = fmaxf(mx4[i], mx4[i + o]);
        float mx = mx4[0];
        mx = fmaxf(mx, __shfl_xor(mx, 16));
        mx = fmaxf(mx, __shfl_xor(mx, 32));

        float s4[4] = {0.f, 0.f, 0.f, 0.f};
        #pragma unroll
        for (int t = 0; t < 16; ++t) {
            #pragma unroll
            for (int i = 0; i < 4; ++i) {
                float e = __expf(p[t][i] - mx);   // 0.25 pre-folded into qH
                p[t][i] = e;
                s4[i] += e;
            }
        }
        float sum = (s4[0] + s4[1]) + (s4[2] + s4[3]);
        sum += __shfl_xor(sum, 16);
        sum += __shfl_xor(sum, 32);
        const float inv = 1.0f / sum;

        float4v acc = {0.f, 0.f, 0.f, 0.f};
        #pragma unroll
        for (int c = 0; c < 8; ++c) {
            #pragma unroll
            for (int pp = 0; pp < 2; ++pp) {
                float4v pv = p[2 * c + pp];
                uint2 wr;
                wr.x = pack2(pv[0], pv[1]);
                wr.y = pack2(pv[2], pv[3]);
                *(uint2*)(pbase + ((col * 64 + (16 * pp + 4 * g) * 2) ^ ((col & 7) << 4))) = wr;
            }
            short8v pf = *(const short8v*)(pbase + ((col * 64 + 16 * g) ^ ((col & 7) << 4)));
            short8v vf = *(const short8v*)&Vp[(c * 64 + lane) * 8];
            acc = __builtin_amdgcn_mfma_f32_16x16x32_bf16(vf, pf, acc, 0, 0, 0);
        }

        uint2 w;
        w.x = pack2(acc[0] * inv, acc[1] * inv);
        w.y = pack2(acc[2] * inv, acc[3] * inv);
        *(uint2*)&Ob[((m0 + col) << 4) + 4 * g] = w;
    }
}

// ---------------------------------------------------------------------------
extern "C" void kernel_launch(void* const* d_in, const int* in_sizes, int n_in,
                              void* d_out, int out_size, void* d_ws, size_t ws_size,
                              hipStream_t stream)
{
    const float* x        = (const float*)d_in[0];
    const float* wq       = (const float*)d_in[1];
    const float* bq       = (const float*)d_in[2];
    const float* off_dw_w = (const float*)d_in[3];
    const float* off_dw_b = (const float*)d_in[4];
    const float* ln_g     = (const float*)d_in[5];
    const float* ln_b     = (const float*)d_in[6];
    const float* off_pw_w = (const float*)d_in[7];
    const float* wk       = (const float*)d_in[8];
    const float* bk       = (const float*)d_in[9];
    const float* wv       = (const float*)d_in[10];
    const float* bv       = (const float*)d_in[11];
    const float* wo       = (const float*)d_in[12];
    const float* bo       = (const float*)d_in[13];
    const float* bn_g     = (const float*)d_in[14];
    const float* bn_b     = (const float*)d_in[15];
    const float* bn_m     = (const float*)d_in[16];
    const float* bn_v     = (const float*)d_in[17];

    float* ws   = (float*)d_ws;
    float* q    = ws;                       // 4194304 f (fp32 for dwconv)
    float* offT = q + 4194304;              // 1048576 f [b][s][c]
    float* xPf  = offT + 1048576;           // 4194304 f [b][p][c]
    unsigned short* us  = (unsigned short*)(xPf + 4194304);
    unsigned short* Wf  = us;               //  262144 us (4 frag-packed weights)
    unsigned short* xT  = Wf  + 262144;     // 4194304 us
    unsigned short* qH  = xT  + 4194304;    // 4194304 us  [b][h][m][16]
    unsigned short* xsT = qH  + 4194304;    // 1048576 us
    unsigned short* aoH = xsT + 1048576;    // 4194304 us  [b][h][m][16]

    prep_k<<<1280, 256, 0, stream>>>(wq, wk, wv, wo, Wf, x, xT, xPf);
    gemm_k<HW, 0><<<dim3(4, 8, BATCH), 256, 0, stream>>>(
        Wf, xT, bq, q, qH, nullptr, nullptr, nullptr, nullptr);
    dwconv_k<<<BATCH * CH, 256, 0, stream>>>(q, off_dw_w, off_dw_b, offT);
    lngs_k<<<BATCH * NS, 256, 0, stream>>>(offT, ln_g, ln_b, off_pw_w, xPf, xsT);
    attn_fused_k<<<BATCH * NH * 2, 1024, 0, stream>>>(qH, xsT, Wf, bk, bv, aoH);
    gemm_k<HW, 2><<<dim3(4, 8, BATCH), 256, 0, stream>>>(
        Wf + 3 * 65536, aoH, bo, (float*)d_out, nullptr,
        bn_g, bn_b, bn_m, bn_v);
}

// Round 19
// 105.384 us; speedup vs baseline: 1.0612x; 1.0233x over previous
//
#include <hip/hip_runtime.h>
#include <hip/hip_bf16.h>
#include <math.h>

#define BATCH 16
#define CH    256
#define HW    1024
#define NS    256
#define NH    16
#define DH    16

typedef __attribute__((ext_vector_type(8))) short short8v;
typedef __attribute__((ext_vector_type(4))) float float4v;

__device__ __forceinline__ unsigned short f2bf(float f) {
    return __builtin_bit_cast(unsigned short, __float2bfloat16(f));
}
__device__ __forceinline__ unsigned pack2(float lo, float hi) {
    return (unsigned)f2bf(lo) | ((unsigned)f2bf(hi) << 16);
}

// ---------------------------------------------------------------------------
// prep: blocks 0..1023   -> weight repack (4 matrices, A-frag order)
//       blocks 1024..1279 -> x[b][c][p] fp32 -> xT[b][p][c] bf16
//                            AND xPf[b][p][c] fp32 (for lngs's coalesced taps)
// Wf[mat][((ot*8+kt)*64+l)*8+i] = W[ot*16+(l&15)][kt*32+8*(l>>4)+i]
// ---------------------------------------------------------------------------
__global__ __launch_bounds__(256) void prep_k(
    const float* __restrict__ wq, const float* __restrict__ wk,
    const float* __restrict__ wv, const float* __restrict__ wo,
    unsigned short* __restrict__ Wf,
    const float* __restrict__ x, unsigned short* __restrict__ xT,
    float* __restrict__ xPf)
{
    int blk = blockIdx.x;
    if (blk < 1024) {
        const float* W;
        switch (blk >> 8) {
            case 0: W = wq; break;
            case 1: W = wk; break;
            case 2: W = wv; break;
            default: W = wo; break;
        }
        int e = (blk & 255) * 256 + threadIdx.x;     // 0..65535
        int i = e & 7, l = (e >> 3) & 63, kt = (e >> 9) & 7, ot = e >> 12;
        float v = W[(ot * 16 + (l & 15)) * 256 + kt * 32 + 8 * (l >> 4) + i];
        Wf[(blk >> 8) * 65536 + e] = f2bf(v);
    } else {
        int xb = blk - 1024;                          // 0..255
        int b = xb >> 4, pblk = (xb >> 2) & 3, cblk = xb & 3;
        int p = pblk * 256 + threadIdx.x;
        const float* xp = x + (size_t)b * CH * HW + p;
        unsigned short* o = xT + ((size_t)b * HW + p) * CH;
        float* o2 = xPf + ((size_t)b * HW + p) * CH;
        #pragma unroll
        for (int cc = 0; cc < 64; cc += 8) {
            int c0 = cblk * 64 + cc;
            float4 lo, hi;
            lo.x = xp[(size_t)(c0 + 0) * HW];
            lo.y = xp[(size_t)(c0 + 1) * HW];
            lo.z = xp[(size_t)(c0 + 2) * HW];
            lo.w = xp[(size_t)(c0 + 3) * HW];
            hi.x = xp[(size_t)(c0 + 4) * HW];
            hi.y = xp[(size_t)(c0 + 5) * HW];
            hi.z = xp[(size_t)(c0 + 6) * HW];
            hi.w = xp[(size_t)(c0 + 7) * HW];
            short8v t;
            t[0] = (short)f2bf(lo.x); t[1] = (short)f2bf(lo.y);
            t[2] = (short)f2bf(lo.z); t[3] = (short)f2bf(lo.w);
            t[4] = (short)f2bf(hi.x); t[5] = (short)f2bf(hi.y);
            t[6] = (short)f2bf(hi.z); t[7] = (short)f2bf(hi.w);
            *(short8v*)&o[c0] = t;
            *(float4*)&o2[c0]     = lo;
            *(float4*)&o2[c0 + 4] = hi;
        }
    }
}

// ---------------------------------------------------------------------------
// bf16 MFMA GEMM conv1x1 (packed Wf): C[o][p] = W[o][:] . X[:][p]  (K=256)
// 64x128 tile, 4 waves, no LDS.
// MODE 0: Q  -> outF fp32 [b][o][p] + outB bf16 qH [b][h][p][16] (pre-scaled 0.25)
// MODE 2: O  -> outF fp32 d_out with BN epilogue; XT is aoH [b][h][m][16]
// ---------------------------------------------------------------------------
template<int P, int MODE>
__global__ __launch_bounds__(256) void gemm_k(
    const unsigned short* __restrict__ Wf, const unsigned short* __restrict__ XT,
    const float* __restrict__ bias,
    float* __restrict__ outF, unsigned short* __restrict__ outB,
    const float* __restrict__ bn_g, const float* __restrict__ bn_b,
    const float* __restrict__ bn_m, const float* __restrict__ bn_v)
{
    const int b = blockIdx.z;

    const int t = threadIdx.x, lane = t & 63, wvi = t >> 6;
    const int g = lane >> 4, col = lane & 15;
    const int o0 = blockIdx.x * 64;
    const int p0 = blockIdx.y * 128 + wvi * 32;
    const unsigned short* xb = XT + ((size_t)b * P + p0) * CH;   // MODE 0

    float4v acc[4][2];
    #pragma unroll
    for (int mi = 0; mi < 4; ++mi)
        #pragma unroll
        for (int ni = 0; ni < 2; ++ni) {
            float4v z = {0.f, 0.f, 0.f, 0.f};
            acc[mi][ni] = z;
        }

    #pragma unroll
    for (int kt = 0; kt < 8; ++kt) {
        short8v af[4], bf[2];
        #pragma unroll
        for (int mi = 0; mi < 4; ++mi)
            af[mi] = *(const short8v*)&Wf[(((((o0 >> 4) + mi) * 8) + kt) * 64 + lane) * 8];
        #pragma unroll
        for (int ni = 0; ni < 2; ++ni) {
            if (MODE == 2) {
                // aoH head-major: channels kt*32+8g..+7 lie inside head hh
                const int hh = kt * 2 + (g >> 1);
                const int p  = p0 + ni * 16 + col;
                bf[ni] = *(const short8v*)&XT[(((size_t)(b * 16 + hh) * P + p) << 4) + 8 * (g & 1)];
            } else {
                bf[ni] = *(const short8v*)&xb[(size_t)(ni * 16 + col) * CH + kt * 32 + 8 * g];
            }
        }
        #pragma unroll
        for (int mi = 0; mi < 4; ++mi)
            #pragma unroll
            for (int ni = 0; ni < 2; ++ni)
                acc[mi][ni] = __builtin_amdgcn_mfma_f32_16x16x32_bf16(
                    af[mi], bf[ni], acc[mi][ni], 0, 0, 0);
    }

    #pragma unroll
    for (int mi = 0; mi < 4; ++mi) {
        const int ob = o0 + mi * 16 + 4 * g;
        float bs[4];
        #pragma unroll
        for (int ii = 0; ii < 4; ++ii) bs[ii] = bias[ob + ii];

        if (MODE == 2) {
            float sc[4], sh[4];
            #pragma unroll
            for (int ii = 0; ii < 4; ++ii) {
                int o = ob + ii;
                float s = bn_g[o] * rsqrtf(bn_v[o] + 1e-5f);
                sc[ii] = s;
                sh[ii] = bn_b[o] - bn_m[o] * s + bs[ii] * s;
            }
            #pragma unroll
            for (int ni = 0; ni < 2; ++ni) {
                int p = p0 + ni * 16 + col;
                #pragma unroll
                for (int ii = 0; ii < 4; ++ii)
                    outF[((size_t)(b * CH + ob + ii)) * P + p] =
                        acc[mi][ni][ii] * sc[ii] + sh[ii];
            }
        } else {
            const int hh = (o0 >> 4) + mi;     // head index (4g < 16)
            #pragma unroll
            for (int ni = 0; ni < 2; ++ni) {
                int p = p0 + ni * 16 + col;
                float v0 = acc[mi][ni][0] + bs[0];
                float v1 = acc[mi][ni][1] + bs[1];
                float v2 = acc[mi][ni][2] + bs[2];
                float v3 = acc[mi][ni][3] + bs[3];
                outF[((size_t)(b * CH + ob + 0)) * P + p] = v0;
                outF[((size_t)(b * CH + ob + 1)) * P + p] = v1;
                outF[((size_t)(b * CH + ob + 2)) * P + p] = v2;
                outF[((size_t)(b * CH + ob + 3)) * P + p] = v3;
                uint2 w;   // qH pre-scaled by 0.25 (exact pow2)
                w.x = pack2(v0 * 0.25f, v1 * 0.25f);
                w.y = pack2(v2 * 0.25f, v3 * 0.25f);
                *(uint2*)&outB[(((size_t)(b * 16 + hh) * P + p) << 4) + 4 * g] = w;
            }
        }
    }
}

// ---------------------------------------------------------------------------
// depthwise 9x9 conv, stride 2, pad 4:
// q fp32 [b][c][32][32] -> offT fp32 [b][s][c]  (transposed write)
// plane staged via one float4 per thread.
// ---------------------------------------------------------------------------
__global__ __launch_bounds__(256) void dwconv_k(
    const float* __restrict__ q, const float* __restrict__ w,
    const float* __restrict__ bias, float* __restrict__ offT)
{
    int bc = blockIdx.x;
    int b  = bc >> 8;
    int c  = bc & (CH - 1);
    __shared__ float plane[HW];
    __shared__ float kw[81];
    int t = threadIdx.x;
    const float* qp = q + (size_t)bc * HW;
    *(float4*)&plane[t * 4] = *(const float4*)&qp[t * 4];
    if (t < 81) kw[t] = w[c * 81 + t];
    __syncthreads();
    int hk = t >> 4, wk = t & 15;
    float s = bias[c];
    int yb = hk * 2 - 4, xb = wk * 2 - 4;
    #pragma unroll
    for (int dy = 0; dy < 9; ++dy) {
        int yy = yb + dy;
        if ((unsigned)yy < 32u) {
            #pragma unroll
            for (int dx = 0; dx < 9; ++dx) {
                int xx = xb + dx;
                if ((unsigned)xx < 32u) s += kw[dy * 9 + dx] * plane[yy * 32 + xx];
            }
        }
    }
    offT[((size_t)(b * NS + t)) * CH + c] = s;
}

// ---------------------------------------------------------------------------
// fused: LN(channel) + GELU + projection + ref + tanh + bilinear grid sample
// offT read coalesced; taps from xPf[b][p][c] fp32 (dense 1KB runs).
// -> xsT bf16 [b][s][c]
// ---------------------------------------------------------------------------
__device__ inline void block_reduce2(float& a, float& b, int t, float* sbuf)
{
    #pragma unroll
    for (int o = 32; o > 0; o >>= 1) {
        a += __shfl_down(a, o);
        b += __shfl_down(b, o);
    }
    int w = t >> 6;
    if ((t & 63) == 0) { sbuf[w * 2] = a; sbuf[w * 2 + 1] = b; }
    __syncthreads();
    a = sbuf[0] + sbuf[2] + sbuf[4] + sbuf[6];
    b = sbuf[1] + sbuf[3] + sbuf[5] + sbuf[7];
    __syncthreads();
}

__global__ __launch_bounds__(256) void lngs_k(
    const float* __restrict__ offT, const float* __restrict__ ln_g,
    const float* __restrict__ ln_b, const float* __restrict__ pw,
    const float* __restrict__ xPf, unsigned short* __restrict__ xsT)
{
    __shared__ float sbuf[8];
    int bs = blockIdx.x;
    int b = bs >> 8, s = bs & 255;
    int c = threadIdx.x;
    float v   = offT[(size_t)bs * CH + c];
    float pw0 = pw[c];            // hoisted: overlap with reduction chain
    float pw1 = pw[CH + c];
    float lg  = ln_g[c];
    float lb  = ln_b[c];
    float a = v, q2 = v * v;
    block_reduce2(a, q2, c, sbuf);
    float mean = a * (1.0f / 256.0f);
    float var  = q2 * (1.0f / 256.0f) - mean * mean;
    float xn = (v - mean) * rsqrtf(var + 1e-5f) * lg + lb;
    float g = 0.5f * xn * (1.0f + erff(xn * 0.70710678118654752f));
    float d0 = g * pw0;
    float d1 = g * pw1;
    block_reduce2(d0, d1, c, sbuf);   // broadcasts sums to all threads

    int hk = s >> 4, wk = s & 15;
    float ry = ((hk + 0.5f) / 16.0f) * 2.0f - 1.0f;
    float rx = ((wk + 0.5f) / 16.0f) * 2.0f - 1.0f;
    float py = tanhf(d0 + ry);
    float px = tanhf(d1 + rx);

    float gx = (px + 1.0f) * 0.5f * 31.0f;
    float gy = (py + 1.0f) * 0.5f * 31.0f;
    float x0f = floorf(gx), y0f = floorf(gy);
    int ix = (int)x0f, iy = (int)y0f;
    float wx1 = gx - x0f, wx0 = 1.0f - wx1;
    float wy1 = gy - y0f, wy0 = 1.0f - wy1;
    const float* base = xPf + ((size_t)b * HW + iy * 32 + ix) * CH + c;
    float v00 = base[0];
    float v01 = base[CH];
    float v10 = base[32 * CH];
    float v11 = base[33 * CH];
    float vv = wy0 * wx0 * v00 + wy0 * wx1 * v01 + wy1 * wx0 * v10 + wy1 * wx1 * v11;
    xsT[(size_t)bs * CH + c] = f2bf(vv);
}

// ---------------------------------------------------------------------------
// fused KV-build + MFMA attention. Grid = (b,h,mhalf): 512 blocks x 1024 thr.
// Wave wvi builds K/V n-tile wvi, then attn over its 32 query rows.
// Q fragments prefetched BEFORE the build (HBM latency hides under 16 MFMA).
// ---------------------------------------------------------------------------
__global__ __launch_bounds__(1024) void attn_fused_k(
    const unsigned short* __restrict__ qH, const unsigned short* __restrict__ xsT,
    const unsigned short* __restrict__ Wf,
    const float* __restrict__ bk, const float* __restrict__ bv,
    unsigned short* __restrict__ aoH)
{
    const int bh    = blockIdx.x >> 1;
    const int mhalf = blockIdx.x & 1;
    const int b = bh >> 4, h = bh & 15;

    __shared__ short Kp[16 * 32 * 8 + 8];   // 8KB + 16B zero slot (QK A-frag)
    __shared__ short Vp[8 * 64 * 8];        // 8KB PV A-frag (8 chunks of n=32)
    __shared__ short Ps[16][16 * 32];       // 16KB per-wave P scratch

    const int tid  = threadIdx.x;
    const int lane = tid & 63;
    const int wvi  = tid >> 6;      // 0..15
    const int col  = lane & 15;
    const int g    = lane >> 4;

    // ---- prefetch both Q fragments (only depend on qH; overlap with build)
    const unsigned short* Qb = qH + ((size_t)(b * 16 + h) * HW << 4);
    short8v qf01[2];
    #pragma unroll
    for (int mt = 0; mt < 2; ++mt) {
        short8v z = {0, 0, 0, 0, 0, 0, 0, 0};
        qf01[mt] = z;
    }
    if (g < 2) {
        const int mbase = mhalf * 512 + wvi * 32;
        qf01[0] = *(const short8v*)&Qb[((mbase + col) << 4) + 8 * g];
        qf01[1] = *(const short8v*)&Qb[((mbase + 16 + col) << 4) + 8 * g];
    }

    {
        const unsigned short* WfK = Wf + 1 * 65536 + h * 4096;
        const unsigned short* WfV = Wf + 2 * 65536 + h * 4096;
        float bk4[4];
        #pragma unroll
        for (int j = 0; j < 4; ++j) bk4[j] = bk[h * 16 + 4 * g + j];
        const float bvv = bv[h * 16 + col];

        const int t  = wvi;
        const int n0 = t * 16;
        float4v accK = {0.f, 0.f, 0.f, 0.f};
        float4v accV = {0.f, 0.f, 0.f, 0.f};
        #pragma unroll
        for (int kt = 0; kt < 8; ++kt) {
            short8v xsf = *(const short8v*)&xsT[((size_t)(b * NS + n0 + col)) * CH + kt * 32 + 8 * g];
            short8v wkf = *(const short8v*)&WfK[(kt * 64 + lane) * 8];
            short8v wvf = *(const short8v*)&WfV[(kt * 64 + lane) * 8];
            accK = __builtin_amdgcn_mfma_f32_16x16x32_bf16(wkf, xsf, accK, 0, 0, 0);
            accV = __builtin_amdgcn_mfma_f32_16x16x32_bf16(xsf, wvf, accV, 0, 0, 0);
        }
        uint2 wrk;
        wrk.x = pack2(accK[0] + bk4[0], accK[1] + bk4[1]);
        wrk.y = pack2(accK[2] + bk4[2], accK[3] + bk4[3]);
        *(uint2*)&Kp[(t * 32 + (g >> 1) * 16 + col) * 8 + 4 * (g & 1)] = wrk;
        uint2 wrv;
        wrv.x = pack2(accV[0] + bvv, accV[1] + bvv);
        wrv.y = pack2(accV[2] + bvv, accV[3] + bvv);
        *(uint2*)&Vp[((t >> 1) * 64 + col + 16 * ((2 * t + (g >> 1)) & 3)) * 8 + 4 * (g & 1)] = wrv;
    }
    if (tid == 0) {
        short8v z = {0, 0, 0, 0, 0, 0, 0, 0};
        *(short8v*)&Kp[16 * 32 * 8] = z;
    }
    __syncthreads();

    unsigned short* Ob = aoH + ((size_t)(b * 16 + h) * HW << 4);
    char* pbase = (char*)Ps[wvi];
    const char* kbase = (const char*)Kp + ((lane < 32) ? lane * 16 : 16 * 32 * 16);
    const int   kstep = (lane < 32) ? 512 : 0;

    #pragma unroll
    for (int mt = 0; mt < 2; ++mt) {
        const int m0 = mhalf * 512 + wvi * 32 + mt * 16;
        const short8v qf = qf01[mt];

        float4v p[16];
        #pragma unroll
        for (int t = 0; t < 16; ++t) {
            short8v kf = *(const short8v*)(kbase + t * kstep);
            float4v z = {0.f, 0.f, 0.f, 0.f};
            p[t] = __builtin_amdgcn_mfma_f32_16x16x32_bf16(kf, qf, z, 0, 0, 0);
        }

        float mx4[16];
        #pragma unroll
        for (int t = 0; t < 16; ++t)
            mx4[t] = fmaxf(fmaxf(p[t][0], p[t][1]), fmaxf(p[t][2], p[t][3]));
        #pragma unroll
        for (int o = 8; o >= 1; o >>= 1)
            #pragma unroll
            for (int i = 0; i < 8; ++i)
                if (i < o) mx4[i] = fmaxf(mx4[i], mx4[i + o]);
        float mx = mx4[0];
        mx = fmaxf(mx, __shfl_xor(mx, 16));
        mx = fmaxf(mx, __shfl_xor(mx, 32));

        float s4[4] = {0.f, 0.f, 0.f, 0.f};
        #pragma unroll
        for (int t = 0; t < 16; ++t) {
            #pragma unroll
            for (int i = 0; i < 4; ++i) {
                float e = __expf(p[t][i] - mx);   // 0.25 pre-folded into qH
                p[t][i] = e;
                s4[i] += e;
            }
        }
        float sum = (s4[0] + s4[1]) + (s4[2] + s4[3]);
        sum += __shfl_xor(sum, 16);
        sum += __shfl_xor(sum, 32);
        const float inv = 1.0f / sum;

        float4v acc = {0.f, 0.f, 0.f, 0.f};
        #pragma unroll
        for (int c = 0; c < 8; ++c) {
            #pragma unroll
            for (int pp = 0; pp < 2; ++pp) {
                float4v pv = p[2 * c + pp];
                uint2 wr;
                wr.x = pack2(pv[0], pv[1]);
                wr.y = pack2(pv[2], pv[3]);
                *(uint2*)(pbase + ((col * 64 + (16 * pp + 4 * g) * 2) ^ ((col & 7) << 4))) = wr;
            }
            short8v pf = *(const short8v*)(pbase + ((col * 64 + 16 * g) ^ ((col & 7) << 4)));
            short8v vf = *(const short8v*)&Vp[(c * 64 + lane) * 8];
            acc = __builtin_amdgcn_mfma_f32_16x16x32_bf16(vf, pf, acc, 0, 0, 0);
        }

        uint2 w;
        w.x = pack2(acc[0] * inv, acc[1] * inv);
        w.y = pack2(acc[2] * inv, acc[3] * inv);
        *(uint2*)&Ob[((m0 + col) << 4) + 4 * g] = w;
    }
}

// ---------------------------------------------------------------------------
extern "C" void kernel_launch(void* const* d_in, const int* in_sizes, int n_in,
                              void* d_out, int out_size, void* d_ws, size_t ws_size,
                              hipStream_t stream)
{
    const float* x        = (const float*)d_in[0];
    const float* wq       = (const float*)d_in[1];
    const float* bq       = (const float*)d_in[2];
    const float* off_dw_w = (const float*)d_in[3];
    const float* off_dw_b = (const float*)d_in[4];
    const float* ln_g     = (const float*)d_in[5];
    const float* ln_b     = (const float*)d_in[6];
    const float* off_pw_w = (const float*)d_in[7];
    const float* wk       = (const float*)d_in[8];
    const float* bk       = (const float*)d_in[9];
    const float* wv       = (const float*)d_in[10];
    const float* bv       = (const float*)d_in[11];
    const float* wo       = (const float*)d_in[12];
    const float* bo       = (const float*)d_in[13];
    const float* bn_g     = (const float*)d_in[14];
    const float* bn_b     = (const float*)d_in[15];
    const float* bn_m     = (const float*)d_in[16];
    const float* bn_v     = (const float*)d_in[17];

    float* ws   = (float*)d_ws;
    float* q    = ws;                       // 4194304 f (fp32 for dwconv)
    float* offT = q + 4194304;              // 1048576 f [b][s][c]
    float* xPf  = offT + 1048576;           // 4194304 f [b][p][c]
    unsigned short* us  = (unsigned short*)(xPf + 4194304);
    unsigned short* Wf  = us;               //  262144 us (4 frag-packed weights)
    unsigned short* xT  = Wf  + 262144;     // 4194304 us
    unsigned short* qH  = xT  + 4194304;    // 4194304 us  [b][h][m][16]
    unsigned short* xsT = qH  + 4194304;    // 1048576 us
    unsigned short* aoH = xsT + 1048576;    // 4194304 us  [b][h][m][16]

    prep_k<<<1280, 256, 0, stream>>>(wq, wk, wv, wo, Wf, x, xT, xPf);
    gemm_k<HW, 0><<<dim3(4, 8, BATCH), 256, 0, stream>>>(
        Wf, xT, bq, q, qH, nullptr, nullptr, nullptr, nullptr);
    dwconv_k<<<BATCH * CH, 256, 0, stream>>>(q, off_dw_w, off_dw_b, offT);
    lngs_k<<<BATCH * NS, 256, 0, stream>>>(offT, ln_g, ln_b, off_pw_w, xPf, xsT);
    attn_fused_k<<<BATCH * NH * 2, 1024, 0, stream>>>(qH, xsT, Wf, bk, bv, aoH);
    gemm_k<HW, 2><<<dim3(4, 8, BATCH), 256, 0, stream>>>(
        Wf + 3 * 65536, aoH, bo, (float*)d_out, nullptr,
        bn_g, bn_b, bn_m, bn_v);
}